// Round 4
// baseline (362.985 us; speedup 1.0000x reference)
//
#include <hip/hip_runtime.h>
#include <hip/hip_bf16.h>
#include <math.h>
#include <stdint.h>

typedef unsigned short u16;
typedef __attribute__((ext_vector_type(8))) short bf16x8;
typedef __attribute__((ext_vector_type(4))) float f32x4;
typedef __attribute__((address_space(3))) void* as3_void;
typedef const __attribute__((address_space(1))) void* as1_cvoid;

__device__ inline u16 f2bf(float f) {
    union { float f; unsigned u; } v; v.f = f;
    unsigned r = v.u + 0x7FFFu + ((v.u >> 16) & 1u);   // round-to-nearest-even
    return (u16)(r >> 16);
}
__device__ inline float bf2f(u16 h) {
    unsigned u = ((unsigned)h) << 16;
    return __builtin_bit_cast(float, u);
}

// DPP helper
template<int CTRL, int RM>
__device__ inline float dpp_mov(float v) {
    return __builtin_bit_cast(float, __builtin_amdgcn_update_dpp(
        0, __builtin_bit_cast(int, v), CTRL, RM, 0xf, false));
}
__device__ inline float wave_sum(float v) {
    v += dpp_mov<0x111, 0xf>(v);
    v += dpp_mov<0x112, 0xf>(v);
    v += dpp_mov<0x114, 0xf>(v);
    v += dpp_mov<0x118, 0xf>(v);
    v += dpp_mov<0x142, 0xa>(v);
    v += dpp_mov<0x143, 0xc>(v);
    return v;                      // lane 63 holds total
}

// ---------------------------------------------------------------------------
// Weight prep
// ---------------------------------------------------------------------------
__global__ __launch_bounds__(256)
void prep_win(const float* __restrict__ W, u16* __restrict__ Wt,
              float* __restrict__ bias, int logD, int R)
{
    int idx = blockIdx.x * 256 + threadIdx.x;
    int D = 1 << logD;
    int total = D * R;
    if (idx < total) {
        int r = idx >> logD;
        int d = idx & (D - 1);
        Wt[idx] = f2bf(W[(size_t)d * R + r]);
    }
    if (idx < R) bias[idx] = W[(size_t)D * R + idx];
}

__global__ __launch_bounds__(256)
void prep_wout(const float* __restrict__ W, u16* __restrict__ Wt, int total)
{
    int idx = blockIdx.x * 256 + threadIdx.x;
    if (idx < total) Wt[idx] = f2bf(W[idx]);
}

// ---------------------------------------------------------------------------
// k1_proj: s = x@proj (f32) + x->bf16 cast. 2 tokens per wave.
// ---------------------------------------------------------------------------
__global__ __launch_bounds__(256)
void k1_proj(const float* __restrict__ x, const float* __restrict__ proj,
             u16* __restrict__ xb, float* __restrict__ sbuf, int Ntok)
{
    __shared__ float plt[16 * 1024];
    const int tid = threadIdx.x;
    #pragma unroll
    for (int k = 0; k < 64; ++k) {
        int idx = k * 256 + tid;
        int e = idx & 15, d = idx >> 4;
        plt[e * 1024 + (d ^ (e << 2))] = proj[idx];
    }
    __syncthreads();

    const int lane = tid & 63;
    const int wid = tid >> 6;
    const int t0 = (blockIdx.x * 4 + wid) * 2;
    if (t0 >= Ntok) return;

    float s[16][2];
    #pragma unroll
    for (int e = 0; e < 16; ++e) { s[e][0] = 0.f; s[e][1] = 0.f; }

    #pragma unroll
    for (int j = 0; j < 4; ++j) {
        const int d0 = (j * 64 + lane) * 4;
        float4 xq[2];
        #pragma unroll
        for (int q = 0; q < 2; ++q) {
            xq[q] = *(const float4*)&x[(size_t)(t0 + q) * 1024 + d0];
            short4 h;
            h.x = (short)f2bf(xq[q].x); h.y = (short)f2bf(xq[q].y);
            h.z = (short)f2bf(xq[q].z); h.w = (short)f2bf(xq[q].w);
            *(short4*)&xb[(size_t)(t0 + q) * 1024 + d0] = h;
        }
        #pragma unroll
        for (int e = 0; e < 16; ++e) {
            float4 p = *(const float4*)&plt[e * 1024 + (d0 ^ (e << 2))];
            #pragma unroll
            for (int q = 0; q < 2; ++q) {
                s[e][q] = fmaf(xq[q].x, p.x, s[e][q]);
                s[e][q] = fmaf(xq[q].y, p.y, s[e][q]);
                s[e][q] = fmaf(xq[q].z, p.z, s[e][q]);
                s[e][q] = fmaf(xq[q].w, p.w, s[e][q]);
            }
        }
    }
    #pragma unroll
    for (int e = 0; e < 16; ++e) {
        s[e][0] = wave_sum(s[e][0]);
        s[e][1] = wave_sum(s[e][1]);
    }
    if (lane == 63) {
        #pragma unroll
        for (int q = 0; q < 2; ++q)
            #pragma unroll
            for (int c = 0; c < 4; ++c) {
                float4 o = { s[c * 4 + 0][q], s[c * 4 + 1][q],
                             s[c * 4 + 2][q], s[c * 4 + 3][q] };
                *(float4*)&sbuf[(size_t)(t0 + q) * 16 + c * 4] = o;
            }
    }
}

// ---------------------------------------------------------------------------
// k1_entmax: thread-per-token LN + exact 1.5-entmax
// ---------------------------------------------------------------------------
__global__ __launch_bounds__(256)
void k1_entmax(const float* __restrict__ sbuf, float* __restrict__ abuf, int Ntok)
{
    int t = blockIdx.x * 256 + threadIdx.x;
    if (t >= Ntok) return;
    float s[16];
    #pragma unroll
    for (int c = 0; c < 4; ++c) {
        float4 v = *(const float4*)&sbuf[(size_t)t * 16 + c * 4];
        s[c * 4 + 0] = v.x; s[c * 4 + 1] = v.y; s[c * 4 + 2] = v.z; s[c * 4 + 3] = v.w;
    }
    float mean = 0.f;
    #pragma unroll
    for (int e = 0; e < 16; ++e) mean += s[e];
    mean *= 0.0625f;
    float var = 0.f;
    #pragma unroll
    for (int e = 0; e < 16; ++e) { float d = s[e] - mean; var = fmaf(d, d, var); }
    var *= 0.0625f;
    float rstd = rsqrtf(var + 1e-5f);

    float z[16];
    #pragma unroll
    for (int e = 0; e < 16; ++e) z[e] = (s[e] - mean) * rstd * 0.5f;
    float zmax = z[0];
    #pragma unroll
    for (int e = 1; e < 16; ++e) zmax = fmaxf(zmax, z[e]);
    #pragma unroll
    for (int e = 0; e < 16; ++e) z[e] -= zmax;

    float zs[16];
    #pragma unroll
    for (int e = 0; e < 16; ++e) zs[e] = z[e];
    #pragma unroll
    for (int k = 2; k <= 16; k <<= 1) {
        #pragma unroll
        for (int j = k >> 1; j > 0; j >>= 1) {
            #pragma unroll
            for (int i = 0; i < 16; ++i) {
                int l = i ^ j;
                if (l > i) {
                    float a = zs[i], b = zs[l];
                    bool asc = ((i & k) == 0);
                    bool sw = asc ? (a > b) : (a < b);
                    if (sw) { zs[i] = b; zs[l] = a; }
                }
            }
        }
    }
    float csum = 0.f, csq = 0.f, tau_star = -3.4e38f;
    #pragma unroll
    for (int kk = 1; kk <= 16; ++kk) {
        float v = zs[16 - kk];
        csum += v; csq += v * v;
        float kf = (float)kk;
        float mn = csum / kf;
        float ms = csq / kf;
        float ss = kf * (ms - mn * mn);
        float delta = fmaxf((1.f - ss) / kf, 0.f);
        float tau = mn - sqrtf(delta);
        if (tau <= v) tau_star = tau;
    }
    #pragma unroll
    for (int c = 0; c < 4; ++c) {
        float4 o;
        float p0 = fmaxf(z[c * 4 + 0] - tau_star, 0.f);
        float p1 = fmaxf(z[c * 4 + 1] - tau_star, 0.f);
        float p2 = fmaxf(z[c * 4 + 2] - tau_star, 0.f);
        float p3 = fmaxf(z[c * 4 + 3] - tau_star, 0.f);
        o.x = p0 * p0; o.y = p1 * p1; o.z = p2 * p2; o.w = p3 * p3;
        *(float4*)&abuf[(size_t)t * 16 + c * 4] = o;
    }
}

// ---------------------------------------------------------------------------
// gcompute: g1 = a@C1, g2 = a@C2 -> bf16. One wave per token.
// ---------------------------------------------------------------------------
__global__ __launch_bounds__(256)
void gcompute(const float* __restrict__ abuf, const float* __restrict__ C1,
              const float* __restrict__ C2, u16* __restrict__ g1,
              u16* __restrict__ g2, int Ntok)
{
    const int tid = threadIdx.x;
    const int lane = tid & 63;
    const int t = blockIdx.x * 4 + (tid >> 6);
    if (t >= Ntok) return;
    float a[16];
    #pragma unroll
    for (int c = 0; c < 4; ++c) {
        float4 v = *(const float4*)&abuf[(size_t)t * 16 + c * 4];
        a[c * 4 + 0] = v.x; a[c * 4 + 1] = v.y; a[c * 4 + 2] = v.z; a[c * 4 + 3] = v.w;
    }
    #pragma unroll
    for (int c8 = 0; c8 < 8; ++c8) {
        int col = c8 * 64 + lane;
        float t1 = 0.f, t2 = 0.f;
        #pragma unroll
        for (int e = 0; e < 16; ++e) {
            t1 = fmaf(a[e], C1[e * 512 + col], t1);
            t2 = fmaf(a[e], C2[e * 512 + col], t2);
        }
        g1[(size_t)t * 512 + col] = f2bf(t1);
        g2[(size_t)t * 512 + col] = f2bf(t2);
    }
}

// ---------------------------------------------------------------------------
// gemm256: C[M,Nn] = A[M,K](bf16) @ Bt[Nn,K](bf16)^T, fused epilogue.
// 256x128 tile, 8 waves (2Mx4N, wave-tile 128x32), BK=64.
// 3-buffer LDS pipeline, 2 K-tiles prefetch ahead, counted vmcnt(6) at tile
// boundaries only (T3+T4), raw s_barrier phases, setprio around MFMA (T5),
// T2 XOR swizzle (linear gload_lds dest + pre-swizzled src + swizzled read).
// MODE 0: gelu->bf16;  MODE 1: (acc+bias[col])*g ->bf16 (g bf16, may alias
//   Cout);  MODE 2: ->f32.
// ---------------------------------------------------------------------------
#define MFMA16(a, b, c) __builtin_amdgcn_mfma_f32_16x16x32_bf16(a, b, c, 0, 0, 0)

template<int MODE>
__global__ __launch_bounds__(512, 1)
void gemm256(const u16* __restrict__ A, const u16* __restrict__ Bt,
             const float* __restrict__ bias, const u16* __restrict__ gmat,
             void* __restrict__ Cout, int M, int Nn, int K, int tilesN)
{
    __shared__ __align__(1024) char smem[147456];   // 3 x (A 32K + B 16K)
    const int tid = threadIdx.x;
    const int lane = tid & 63;
    const int wid = tid >> 6;
    const int wr = wid >> 2;          // 0..1  (M half)
    const int wc = wid & 3;           // 0..3  (N quarter)

    int bid = blockIdx.x;
    {
        int nwg = gridDim.x;
        if (nwg >= 16) {
            int q = nwg >> 3, r = nwg & 7;
            int xcd = bid & 7, loc = bid >> 3;
            bid = (xcd < r ? xcd * (q + 1) : r * (q + 1) + (xcd - r) * q) + loc;
        }
    }
    const int m0 = (bid / tilesN) * 256;
    const int n0 = (bid % tilesN) * 128;

    f32x4 acc[8][2];
    #pragma unroll
    for (int i = 0; i < 8; ++i) {
        acc[i][0] = (f32x4){0.f, 0.f, 0.f, 0.f};
        acc[i][1] = (f32x4){0.f, 0.f, 0.f, 0.f};
    }

    // staging: linear LDS dest (wave-uniform base), source chunk XOR-swizzled
    auto stageA = [&](int buf, int k0, int ai) {
        int q = ai * 512 + tid;                 // 16B-chunk id, 8 per 64-elem row
        int row = q >> 3;
        int c = (q & 7) ^ (row & 7);
        __builtin_amdgcn_global_load_lds(
            (as1_cvoid)(A + (size_t)(m0 + row) * K + k0 + c * 8),
            (as3_void)&smem[buf * 49152 + (ai * 512 + wid * 64) * 16], 16, 0, 0);
    };
    auto stageB = [&](int buf, int k0, int bi) {
        int q = bi * 512 + tid;
        int row = q >> 3;
        int c = (q & 7) ^ (row & 7);
        __builtin_amdgcn_global_load_lds(
            (as1_cvoid)(Bt + (size_t)(n0 + row) * K + k0 + c * 8),
            (as3_void)&smem[buf * 49152 + 32768 + (bi * 512 + wid * 64) * 16], 16, 0, 0);
    };

    const int arow = wr * 128 + (lane & 15);
    const int brow = wc * 32 + (lane & 15);
    const int sHi  = lane >> 4;                 // 16B slot sub-index
    const int aX = arow & 7, bX = brow & 7;
    const int abyte = arow * 128;
    const int bbyte = 32768 + brow * 128;

    auto LDA = [&](int buf, int i, int kk) -> bf16x8 {
        return *(const bf16x8*)&smem[buf * 49152 + abyte + i * 2048
                                     + ((((kk << 2) | sHi) ^ aX) << 4)];
    };
    auto LDB = [&](int buf, int j, int kk) -> bf16x8 {
        return *(const bf16x8*)&smem[buf * 49152 + bbyte + j * 2048
                                     + ((((kk << 2) | sHi) ^ bX) << 4)];
    };

    const int nt = K >> 6;
    // prologue: stage tiles 0,1 (6 loads each)
    #pragma unroll
    for (int ai = 0; ai < 4; ++ai) stageA(0, 0, ai);
    stageB(0, 0, 0); stageB(0, 0, 1);
    #pragma unroll
    for (int ai = 0; ai < 4; ++ai) stageA(1, 64, ai);
    stageB(1, 64, 0); stageB(1, 64, 1);

    for (int t = 0; t < nt; ++t) {
        const int buf = t % 3;
        const int sb = (t + 2) % 3;
        const int sk = (t + 2) << 6;
        const bool st = (t + 2) < nt;
        // tile boundary: own tile-t loads landed (next tile's 6 may fly)
        if (t < nt - 1) asm volatile("s_waitcnt vmcnt(6)" ::: "memory");
        else            asm volatile("s_waitcnt vmcnt(0)" ::: "memory");
        __builtin_amdgcn_sched_barrier(0);
        __builtin_amdgcn_s_barrier();

        bf16x8 aR[4], bR[2];
        // ---- phase 0: kk=0, M-frags 0-3 (+ B kk0); stage next A 0,1 ----
        aR[0] = LDA(buf, 0, 0); aR[1] = LDA(buf, 1, 0);
        aR[2] = LDA(buf, 2, 0); aR[3] = LDA(buf, 3, 0);
        bR[0] = LDB(buf, 0, 0); bR[1] = LDB(buf, 1, 0);
        if (st) { stageA(sb, sk, 0); stageA(sb, sk, 1); }
        __builtin_amdgcn_s_barrier();
        __builtin_amdgcn_s_setprio(1);
        #pragma unroll
        for (int i = 0; i < 4; ++i) {
            acc[i][0] = MFMA16(aR[i], bR[0], acc[i][0]);
            acc[i][1] = MFMA16(aR[i], bR[1], acc[i][1]);
        }
        __builtin_amdgcn_s_setprio(0);
        __builtin_amdgcn_s_barrier();
        // ---- phase 1: kk=0, M-frags 4-7; stage next A 2,3 ----
        aR[0] = LDA(buf, 4, 0); aR[1] = LDA(buf, 5, 0);
        aR[2] = LDA(buf, 6, 0); aR[3] = LDA(buf, 7, 0);
        if (st) { stageA(sb, sk, 2); stageA(sb, sk, 3); }
        __builtin_amdgcn_s_barrier();
        __builtin_amdgcn_s_setprio(1);
        #pragma unroll
        for (int i = 0; i < 4; ++i) {
            acc[4 + i][0] = MFMA16(aR[i], bR[0], acc[4 + i][0]);
            acc[4 + i][1] = MFMA16(aR[i], bR[1], acc[4 + i][1]);
        }
        __builtin_amdgcn_s_setprio(0);
        __builtin_amdgcn_s_barrier();
        // ---- phase 2: kk=1, M-frags 0-3 (+ B kk1); stage next B 0 ----
        aR[0] = LDA(buf, 0, 1); aR[1] = LDA(buf, 1, 1);
        aR[2] = LDA(buf, 2, 1); aR[3] = LDA(buf, 3, 1);
        bR[0] = LDB(buf, 0, 1); bR[1] = LDB(buf, 1, 1);
        if (st) stageB(sb, sk, 0);
        __builtin_amdgcn_s_barrier();
        __builtin_amdgcn_s_setprio(1);
        #pragma unroll
        for (int i = 0; i < 4; ++i) {
            acc[i][0] = MFMA16(aR[i], bR[0], acc[i][0]);
            acc[i][1] = MFMA16(aR[i], bR[1], acc[i][1]);
        }
        __builtin_amdgcn_s_setprio(0);
        __builtin_amdgcn_s_barrier();
        // ---- phase 3: kk=1, M-frags 4-7; stage next B 1 ----
        aR[0] = LDA(buf, 4, 1); aR[1] = LDA(buf, 5, 1);
        aR[2] = LDA(buf, 6, 1); aR[3] = LDA(buf, 7, 1);
        if (st) stageB(sb, sk, 1);
        __builtin_amdgcn_s_barrier();
        __builtin_amdgcn_s_setprio(1);
        #pragma unroll
        for (int i = 0; i < 4; ++i) {
            acc[4 + i][0] = MFMA16(aR[i], bR[0], acc[4 + i][0]);
            acc[4 + i][1] = MFMA16(aR[i], bR[1], acc[4 + i][1]);
        }
        __builtin_amdgcn_s_setprio(0);
        __builtin_amdgcn_s_barrier();
    }

    // epilogue: C/D layout col=lane&15, row=(lane>>4)*4 + r
    const int cl = lane & 15;
    const int rq = (lane >> 4) * 4;
    #pragma unroll
    for (int i = 0; i < 8; ++i) {
        #pragma unroll
        for (int j = 0; j < 2; ++j) {
            int col = n0 + wc * 32 + j * 16 + cl;
            float bv = (MODE == 1) ? bias[col] : 0.f;
            #pragma unroll
            for (int r = 0; r < 4; ++r) {
                int row = m0 + wr * 128 + i * 16 + rq + r;
                float v = acc[i][j][r];
                if (MODE == 0) {
                    v = 0.5f * v * (1.f + erff(v * 0.70710678118654752f));
                    ((u16*)Cout)[(size_t)row * Nn + col] = f2bf(v);
                } else if (MODE == 1) {
                    v = (v + bv) * bf2f(gmat[(size_t)row * Nn + col]);
                    ((u16*)Cout)[(size_t)row * Nn + col] = f2bf(v);
                } else {
                    ((float*)Cout)[(size_t)row * Nn + col] = v;
                }
            }
        }
    }
}

// ---------------------------------------------------------------------------
extern "C" void kernel_launch(void* const* d_in, const int* in_sizes, int n_in,
                              void* d_out, int out_size, void* d_ws, size_t ws_size,
                              hipStream_t stream)
{
    const float* x     = (const float*)d_in[0];
    const float* proj  = (const float*)d_in[1];
    const float* C1    = (const float*)d_in[2];
    const float* Win1  = (const float*)d_in[3];
    const float* Wout1 = (const float*)d_in[4];
    const float* C2    = (const float*)d_in[5];
    const float* Win2  = (const float*)d_in[6];
    const float* Wout2 = (const float*)d_in[7];

    const int D = 1024, O = 4096, R = 512, D2 = 1024;
    const int Ntok = in_sizes[0] / D;   // 16384

    char* ws = (char*)d_ws;
    size_t off = 0;
    auto alloc = [&](size_t bytes) -> void* {
        void* p = ws + off;
        off += (bytes + 255) & ~(size_t)255;
        return p;
    };
    // ---- persistent ----
    u16*   z1  = (u16*)  alloc((size_t)Ntok * R * 2);    // aliases g1
    u16*   z2  = (u16*)  alloc((size_t)Ntok * R * 2);    // aliases g2
    u16*   w1o = (u16*)  alloc((size_t)O * R * 2);       // Wout1  [4096,512]
    u16*   w2t = (u16*)  alloc((size_t)R * O * 2);       // Win2^T [512,4096]
    u16*   w2o = (u16*)  alloc((size_t)D2 * R * 2);      // Wout2  [1024,512]
    float* b1  = (float*)alloc(R * 4);
    float* b2  = (float*)alloc(R * 4);
    size_t persist_end = off;

    // ---- transient (dead before first G2) ----
    u16*   xb   = (u16*)  alloc((size_t)Ntok * D * 2);
    u16*   w1t  = (u16*)  alloc((size_t)R * D * 2);      // Win1^T [512,1024]
    float* sbuf = (float*)alloc((size_t)Ntok * 16 * 4);
    float* abuf = (float*)alloc((size_t)Ntok * 16 * 4);

    // hbuf overlays the transient region
    size_t hAvail = (ws_size > persist_end) ? (ws_size - persist_end) : 0;
    long long chRows = (long long)(hAvail / ((size_t)O * 2));
    chRows &= ~255LL;
    int CH = (chRows > Ntok) ? Ntok : (int)chRows;
    if (CH < 256) CH = 256;
    u16* hbuf = (u16*)(ws + persist_end);

    u16* g1 = z1;
    u16* g2 = z2;

    // weight prep
    prep_win <<<(D * R + 255) / 256, 256, 0, stream>>>(Win1, w1t, b1, 10, R);
    prep_win <<<(O * R + 255) / 256, 256, 0, stream>>>(Win2, w2t, b2, 12, R);
    prep_wout<<<(O * R + 255) / 256, 256, 0, stream>>>(Wout1, w1o, O * R);
    prep_wout<<<(D2 * R + 255) / 256, 256, 0, stream>>>(Wout2, w2o, D2 * R);

    // gating path
    k1_proj  <<<Ntok / 8, 256, 0, stream>>>(x, proj, xb, sbuf, Ntok);
    k1_entmax<<<(Ntok + 255) / 256, 256, 0, stream>>>(sbuf, abuf, Ntok);
    gcompute <<<(Ntok + 3) / 4, 256, 0, stream>>>(abuf, C1, C2, g1, g2, Ntok);

    // G1: z1 = (x @ Win1 + b1) * g1   [N,512], K=1024  (in-place over g1)
    gemm256<1><<<(Ntok / 256) * (R / 128), 512, 0, stream>>>(
        xb, w1t, b1, g1, z1, Ntok, R, D, R / 128);

    // chunked: G2: h = gelu(z1 @ Wout1^T) [N,4096], K=512
    //          G3: z2 = (h @ Win2 + b2) * g2 [N,512], K=4096 (in-place over g2)
    for (int r0 = 0; r0 < Ntok; r0 += CH) {
        int cm = Ntok - r0; if (cm > CH) cm = CH;
        gemm256<0><<<(cm / 256) * (O / 128), 512, 0, stream>>>(
            z1 + (size_t)r0 * R, w1o, nullptr, nullptr,
            hbuf, cm, O, R, O / 128);
        gemm256<1><<<(cm / 256) * (R / 128), 512, 0, stream>>>(
            hbuf, w2t, b2, g2 + (size_t)r0 * R,
            z2 + (size_t)r0 * R, cm, R, O, R / 128);
    }

    // G4: out = z2 @ Wout2^T  [N,1024] f32, K=512
    gemm256<2><<<(Ntok / 256) * (D2 / 128), 512, 0, stream>>>(
        z2, w2o, nullptr, nullptr, d_out, Ntok, D2, R, D2 / 128);
}